// Round 1
// baseline (589.394 us; speedup 1.0000x reference)
//
#include <hip/hip_runtime.h>

#define NB 8
#define NP 24564
#define NCLS 80          // foreground classes
#define TOPK 400
#define KEEPK 200
#define OUTS 19
#define NCELL (OUTS * OUTS)   // 361
#define DETN (NCLS * TOPK)    // 32000 per batch
#define ROWS 64
#define CHUNKS ((NP + ROWS - 1) / ROWS)   // 384

__device__ __forceinline__ unsigned f2ord(float f) {
    unsigned u = __float_as_uint(f);
    return (u & 0x80000000u) ? ~u : (u | 0x80000000u);
}
__device__ __forceinline__ float ord2f(unsigned k) {
    unsigned u = (k & 0x80000000u) ? (k & 0x7fffffffu) : ~k;
    return __uint_as_float(u);
}

// ---------------- Kernel A: transpose scores + decode boxes ----------------
__global__ __launch_bounds__(256) void kA(const float* __restrict__ x,
                                          float* __restrict__ scoresT,
                                          float4* __restrict__ boxes) {
    int blk = blockIdx.x;
    int b = blk / CHUNKS, chunk = blk % CHUNKS;
    int p0 = chunk * ROWS;
    int nrows = NP - p0; if (nrows > ROWS) nrows = ROWS;
    __shared__ float tile[ROWS * 93];
    const float* src = x + (size_t)(b * NP + p0) * 93;
    int total = nrows * 93;
    for (int e = threadIdx.x; e < total; e += 256) tile[e] = src[e];
    __syncthreads();
    int row = threadIdx.x & 63;
    int cg = threadIdx.x >> 6;
    if (row < nrows) {
        for (int c = cg; c < NCLS; c += 4) {
            float v = tile[row * 93 + 5 + c];
            float m = (v > 0.01f) ? v : -1.0f;
            scoresT[(size_t)(b * NCLS + c) * NP + p0 + row] = m;
        }
    }
    if (threadIdx.x < nrows) {
        const float* r = tile + threadIdx.x * 93;
        float l0 = r[0], l1 = r[1], l2 = r[2], l3 = r[3];
        float px1 = r[85], py1 = r[86], px2 = r[87], py2 = r[88];
        float v0 = r[89], v1 = r[90], v2 = r[91], v3 = r[92];
        float pw = px2 - px1, ph = py2 - py1;
        float pcx = 0.5f * (px2 + px1), pcy = 0.5f * (py2 + py1);
        float cx = l0 * pw * v0 + pcx;
        float cy = l1 * pw * v1 + pcy;      // reference uses pw here too
        float w = expf(l2 * v2) * pw;
        float h = expf(l3 * v3) * ph;
        float x1 = fminf(fmaxf(cx - 0.5f * w, 0.f), 1.f);
        float y1 = fminf(fmaxf(cy - 0.5f * h, 0.f), 1.f);
        float x2 = fminf(fmaxf(cx + 0.5f * w, 0.f), 1.f);
        float y2 = fminf(fmaxf(cy + 0.5f * h, 0.f), 1.f);
        boxes[(size_t)b * NP + p0 + threadIdx.x] = make_float4(x1, y1, x2, y2);
    }
}

// ------------- shared top-k select: fills cand[0..cap) sorted desc ---------
// key = (ordkey<<32) | ~idx  -> descending sort == (score desc, idx asc)
__device__ __forceinline__ void topk_collect(const float* __restrict__ src, int n,
                                             unsigned needed,
                                             unsigned long long* cand, unsigned cap,
                                             unsigned (*hist)[256], unsigned* suf,
                                             unsigned* scal, int tid) {
    unsigned prefix = 0;
    for (int pass = 0; pass < 4; ++pass) {
        int shift = 24 - pass * 8;
        for (int i = tid; i < 1024; i += 256) ((unsigned*)hist)[i] = 0u;
        __syncthreads();
        int w = tid >> 6;
        for (int p = tid; p < n; p += 256) {
            unsigned key = f2ord(src[p]);
            if (pass == 0 || (key >> (shift + 8)) == prefix)
                atomicAdd(&hist[w][(key >> shift) & 255u], 1u);
        }
        __syncthreads();
        unsigned h = hist[0][tid] + hist[1][tid] + hist[2][tid] + hist[3][tid];
        suf[tid] = h;
        __syncthreads();
        for (int d = 1; d < 256; d <<= 1) {
            unsigned v = (tid + d < 256) ? suf[tid + d] : 0u;
            __syncthreads();
            suf[tid] += v;
            __syncthreads();
        }
        unsigned mySuf = suf[tid];
        unsigned nextSuf = (tid < 255) ? suf[tid + 1] : 0u;
        if (mySuf >= needed && nextSuf < needed) { scal[0] = (unsigned)tid; scal[1] = nextSuf; }
        __syncthreads();
        prefix = (prefix << 8) | scal[0];
        needed -= scal[1];
        __syncthreads();
    }
    // prefix == exact 32-bit threshold key T
    if (tid == 0) scal[2] = 0u;
    __syncthreads();
    for (int p = tid; p < n; p += 256) {
        unsigned key = f2ord(src[p]);
        if (key >= prefix) {
            unsigned pos = atomicAdd(&scal[2], 1u);
            if (pos < cap) cand[pos] = ((unsigned long long)key << 32) | (unsigned)(~p);
        }
    }
    __syncthreads();
    unsigned cc = scal[2]; if (cc > cap) cc = cap;
    for (unsigned i = tid; i < cap; i += 256) if (i >= cc) cand[i] = 0ull;
    __syncthreads();
    for (unsigned k = 2; k <= cap; k <<= 1)
        for (unsigned j = k >> 1; j; j >>= 1) {
            for (unsigned i = tid; i < cap; i += 256) {
                unsigned l = i ^ j;
                if (l > i) {
                    unsigned long long a = cand[i], bq = cand[l];
                    bool sw = ((i & k) == 0) ? (a < bq) : (a > bq);
                    if (sw) { cand[i] = bq; cand[l] = a; }
                }
            }
            __syncthreads();
        }
}

// -------- Kernel B: per (b,c) top-400, IoU bitmask, greedy NMS -------------
__global__ __launch_bounds__(256) void kB(const float* __restrict__ scoresT,
                                          const float4* __restrict__ boxes,
                                          float* __restrict__ detS,
                                          float4* __restrict__ detB) {
    __shared__ unsigned hist[4][256];
    __shared__ unsigned suf[256];
    __shared__ unsigned scal[3];
    __shared__ unsigned long long cand[512];
    __shared__ float4 selBox[TOPK];
    __shared__ float selArea[TOPK];
    __shared__ unsigned iouRow[TOPK][13];
    __shared__ unsigned keptWords[13];

    int b = blockIdx.x / NCLS, c = blockIdx.x % NCLS;
    int tid = threadIdx.x;
    const float* src = scoresT + (size_t)(b * NCLS + c) * NP;

    topk_collect(src, NP, TOPK, cand, 512, hist, suf, scal, tid);

    for (int k = tid; k < TOPK; k += 256) {
        unsigned idx = ~(unsigned)cand[k];
        float4 bx = boxes[(size_t)b * NP + idx];
        selBox[k] = bx;
        selArea[k] = (bx.z - bx.x) * (bx.w - bx.y);
    }
    __syncthreads();

    for (int r = tid; r < TOPK; r += 256) {
        float4 br = selBox[r];
        float ar = selArea[r];
        unsigned word = 0;
        for (int j = 0; j < TOPK; ++j) {
            float4 bj = selBox[j];
            float ix = fminf(br.z, bj.z) - fmaxf(br.x, bj.x);
            float iy = fminf(br.w, bj.w) - fmaxf(br.y, bj.y);
            float inter = fmaxf(ix, 0.f) * fmaxf(iy, 0.f);
            float uni = ar + selArea[j] - inter;
            bool sup = inter > 0.45f * uni;   // == (iou > 0.45) with union>0 guard
            word |= (unsigned)sup << (j & 31);
            if ((j & 31) == 31) { iouRow[r][j >> 5] = word; word = 0; }
        }
        iouRow[r][12] = word;
    }
    __syncthreads();

    if (tid < 64) {
        unsigned lane = tid;
        unsigned myKept = 0;
        const unsigned VALID_KEY = f2ord(0.01f);
        for (int i = 0; i < TOPK; ++i) {
            unsigned w = (lane < 13) ? iouRow[i][lane] : 0u;
            bool hit = (w & myKept) != 0u;
            unsigned long long bal = __ballot(hit);
            unsigned keyi = (unsigned)(cand[i] >> 32);
            bool kept = (keyi > VALID_KEY) && (bal == 0ull);
            if (kept && lane == (unsigned)(i >> 5)) myKept |= 1u << (i & 31);
        }
        if (lane < 13) keptWords[lane] = myKept;
    }
    __syncthreads();

    size_t obase = (size_t)b * DETN + (size_t)c * TOPK;
    for (int k = tid; k < TOPK; k += 256) {
        bool kept = (keptWords[k >> 5] >> (k & 31)) & 1u;
        float s = ord2f((unsigned)(cand[k] >> 32));
        detS[obase + k] = kept ? s : -1.0f;
        detB[obase + k] = selBox[k];
    }
}

// -------- Kernel C: per-batch stable top-200 + rasterize -------------------
__global__ __launch_bounds__(256) void kC(const float* __restrict__ detS,
                                          const float4* __restrict__ detB,
                                          float* __restrict__ out) {
    __shared__ unsigned hist[4][256];
    __shared__ unsigned suf[256];
    __shared__ unsigned scal[3];
    __shared__ unsigned long long cand[1024];
    __shared__ float eS[KEEPK];
    __shared__ int eC0[KEEPK], eC1[KEEPK], eC2[KEEPK], eC3[KEEPK];
    __shared__ int eCh[KEEPK];

    int b = blockIdx.x;
    int tid = threadIdx.x;

    topk_collect(detS + (size_t)b * DETN, DETN, KEEPK, cand, 1024, hist, suf, scal, tid);

    for (int k = tid; k < KEEPK; k += 256) {
        unsigned long long K = cand[k];
        unsigned key = (unsigned)(K >> 32);
        unsigned idx = ~(unsigned)K;
        float s = ord2f(key);
        float4 bx = detB[(size_t)b * DETN + idx];
        eS[k] = s;
        eC0[k] = (int)rintf(bx.x * (float)OUTS);
        eC1[k] = (int)rintf(bx.y * (float)OUTS);
        eC2[k] = (int)rintf(bx.z * (float)OUTS);
        eC3[k] = (int)rintf(bx.w * (float)OUTS);
        eCh[k] = (int)(idx / TOPK);
    }
    __syncthreads();

    for (int cell = tid; cell < NCELL; cell += 256) {
        int y = cell / OUTS, x = cell % OUTS;
        float* o = out + ((size_t)b * NCELL + cell) * 81;
        for (int ch = 0; ch < 81; ++ch) o[ch] = 0.f;
        for (int k = 0; k < KEEPK; ++k) {
            float s = eS[k];
            if (s < 0.6f) continue;
            if (y >= eC1[k] && y < eC3[k] && x >= eC0[k] && x < eC2[k])
                o[eCh[k]] = s;
        }
    }
}

extern "C" void kernel_launch(void* const* d_in, const int* in_sizes, int n_in,
                              void* d_out, int out_size, void* d_ws, size_t ws_size,
                              hipStream_t stream) {
    const float* x = (const float*)d_in[0];
    float* out = (float*)d_out;

    float4* boxes   = (float4*)d_ws;                         // NB*NP float4
    float4* detB    = boxes + (size_t)NB * NP;               // NB*DETN float4
    float*  scoresT = (float*)(detB + (size_t)NB * DETN);    // NB*NCLS*NP floats
    float*  detS    = scoresT + (size_t)NB * NCLS * NP;      // NB*DETN floats

    kA<<<NB * CHUNKS, 256, 0, stream>>>(x, scoresT, boxes);
    kB<<<NB * NCLS, 256, 0, stream>>>(scoresT, boxes, detS, detB);
    kC<<<NB, 256, 0, stream>>>(detS, detB, out);
}

// Round 2
// 410.235 us; speedup vs baseline: 1.4367x; 1.4367x over previous
//
#include <hip/hip_runtime.h>

#define NB 8
#define NP 24564
#define NCLS 80          // foreground classes
#define TOPK 400
#define KEEPK 200
#define OUTS 19
#define NCELL (OUTS * OUTS)   // 361
#define DETN (NCLS * TOPK)    // 32000 per batch
#define ROWS 64
#define CHUNKS ((NP + ROWS - 1) / ROWS)   // 384
#define CAP 1024

__device__ __forceinline__ unsigned f2ord(float f) {
    unsigned u = __float_as_uint(f);
    return (u & 0x80000000u) ? ~u : (u | 0x80000000u);
}
__device__ __forceinline__ float ord2f(unsigned k) {
    unsigned u = (k & 0x80000000u) ? (k & 0x7fffffffu) : ~k;
    return __uint_as_float(u);
}
// 1024 bins over key top-16-bits; all scores in (0.01,1] have key>>16 in
// [0xBC00, 0xBF80]; -1 sentinels clamp to bin 0.
__device__ __forceinline__ unsigned bin16(unsigned key) {
    int b = (int)(key >> 16) - 0xBC00;
    b = b < 0 ? 0 : (b > 1023 ? 1023 : b);
    return (unsigned)b;
}

// ---------------- Kernel A: transpose scores + decode boxes ----------------
__global__ __launch_bounds__(256) void kA(const float* __restrict__ x,
                                          float* __restrict__ scoresT,
                                          float4* __restrict__ boxes) {
    int blk = blockIdx.x;
    int b = blk / CHUNKS, chunk = blk % CHUNKS;
    int p0 = chunk * ROWS;
    int nrows = NP - p0; if (nrows > ROWS) nrows = ROWS;
    __shared__ float tile[ROWS * 93];
    const float* src = x + (size_t)(b * NP + p0) * 93;
    int total4 = (nrows * 93) >> 2;          // 64*93 and 52*93 both %4==0
    const float4* s4 = (const float4*)src;
    float4* t4 = (float4*)tile;
    for (int e = threadIdx.x; e < total4; e += 256) t4[e] = s4[e];
    __syncthreads();
    int row = threadIdx.x & 63;
    int cg = threadIdx.x >> 6;
    if (row < nrows) {
        for (int c = cg; c < NCLS; c += 4) {
            float v = tile[row * 93 + 5 + c];
            float m = (v > 0.01f) ? v : -1.0f;
            scoresT[(size_t)(b * NCLS + c) * NP + p0 + row] = m;
        }
    }
    if (threadIdx.x < nrows) {
        const float* r = tile + threadIdx.x * 93;
        float l0 = r[0], l1 = r[1], l2 = r[2], l3 = r[3];
        float px1 = r[85], py1 = r[86], px2 = r[87], py2 = r[88];
        float v0 = r[89], v1 = r[90], v2 = r[91], v3 = r[92];
        float pw = px2 - px1, ph = py2 - py1;
        float pcx = 0.5f * (px2 + px1), pcy = 0.5f * (py2 + py1);
        float cx = l0 * pw * v0 + pcx;
        float cy = l1 * pw * v1 + pcy;      // reference uses pw here too
        float w = expf(l2 * v2) * pw;
        float h = expf(l3 * v3) * ph;
        float x1 = fminf(fmaxf(cx - 0.5f * w, 0.f), 1.f);
        float y1 = fminf(fmaxf(cy - 0.5f * h, 0.f), 1.f);
        float x2 = fminf(fmaxf(cx + 0.5f * w, 0.f), 1.f);
        float y2 = fminf(fmaxf(cy + 0.5f * h, 0.f), 1.f);
        boxes[(size_t)b * NP + p0 + threadIdx.x] = make_float4(x1, y1, x2, y2);
    }
}

// --- exact top-k select: hist1024 on key[31:16] + optional byte refine -----
// fills cand[0..CAP) sorted desc by (key<<32)|~idx  (score desc, idx asc)
__device__ void select_desc(const float* __restrict__ src, int n, unsigned needed,
                            unsigned long long* cand,
                            unsigned* hist,   // LDS[1024]
                            unsigned* aux,    // LDS[256]
                            unsigned* scal,   // LDS[4]
                            int tid) {
    // phase 1: 1024-bin histogram
    for (int i = tid; i < 1024; i += 256) hist[i] = 0u;
    __syncthreads();
    const float4* src4 = (const float4*)src;
    int n4 = n >> 2;
    for (int i = tid; i < n4; i += 256) {
        float4 v = src4[i];
        atomicAdd(&hist[bin16(f2ord(v.x))], 1u);
        atomicAdd(&hist[bin16(f2ord(v.y))], 1u);
        atomicAdd(&hist[bin16(f2ord(v.z))], 1u);
        atomicAdd(&hist[bin16(f2ord(v.w))], 1u);
    }
    __syncthreads();
    // phase 2: suffix scan over 1024 (4 bins/thread + 256-group Hillis-Steele)
    unsigned h0 = hist[4 * tid], h1 = hist[4 * tid + 1];
    unsigned h2 = hist[4 * tid + 2], h3 = hist[4 * tid + 3];
    aux[tid] = h0 + h1 + h2 + h3;
    __syncthreads();
    for (int d = 1; d < 256; d <<= 1) {
        unsigned v = (tid + d < 256) ? aux[tid + d] : 0u;
        __syncthreads();
        aux[tid] += v;
        __syncthreads();
    }
    unsigned above = (tid < 255) ? aux[tid + 1] : 0u;
    unsigned s3 = above + h3, s2 = s3 + h2, s1 = s2 + h1, s0 = s1 + h0;
    if (s0 >= needed && s1 < needed) { scal[0] = 4 * tid;     scal[1] = s1;    scal[2] = s0; }
    if (s1 >= needed && s2 < needed) { scal[0] = 4 * tid + 1; scal[1] = s2;    scal[2] = s1; }
    if (s2 >= needed && s3 < needed) { scal[0] = 4 * tid + 2; scal[1] = s3;    scal[2] = s2; }
    if (s3 >= needed && above < needed) { scal[0] = 4 * tid + 3; scal[1] = above; scal[2] = s3; }
    __syncthreads();
    unsigned cb = scal[0], countHigh = scal[1], countAt = scal[2];
    unsigned cut8 = 0;
    if (countAt > CAP) {   // uniform branch: refine cut bin by byte key[15:8]
        aux[tid] = 0u;
        __syncthreads();
        for (int i = tid; i < n4; i += 256) {
            float4 v = src4[i];
            unsigned k0 = f2ord(v.x), k1 = f2ord(v.y), k2 = f2ord(v.z), k3 = f2ord(v.w);
            if (bin16(k0) == cb) atomicAdd(&aux[(k0 >> 8) & 255u], 1u);
            if (bin16(k1) == cb) atomicAdd(&aux[(k1 >> 8) & 255u], 1u);
            if (bin16(k2) == cb) atomicAdd(&aux[(k2 >> 8) & 255u], 1u);
            if (bin16(k3) == cb) atomicAdd(&aux[(k3 >> 8) & 255u], 1u);
        }
        __syncthreads();
        for (int d = 1; d < 256; d <<= 1) {
            unsigned v = (tid + d < 256) ? aux[tid + d] : 0u;
            __syncthreads();
            aux[tid] += v;
            __syncthreads();
        }
        unsigned suf8 = aux[tid];
        unsigned sufN = (tid < 255) ? aux[tid + 1] : 0u;
        unsigned need2 = needed - countHigh;
        if (suf8 >= need2 && sufN < need2) scal[3] = (unsigned)tid;
        __syncthreads();
        cut8 = scal[3];
    }
    // phase 3: collect
    __syncthreads();
    if (tid == 0) scal[1] = 0u;
    __syncthreads();
    for (int i = tid; i < n4; i += 256) {
        float4 v = src4[i];
        unsigned kk[4] = { f2ord(v.x), f2ord(v.y), f2ord(v.z), f2ord(v.w) };
#pragma unroll
        for (int c = 0; c < 4; ++c) {
            unsigned key = kk[c];
            unsigned b16 = bin16(key);
            bool take = (b16 > cb) || (b16 == cb && ((key >> 8) & 255u) >= cut8);
            if (take) {
                unsigned pos = atomicAdd(&scal[1], 1u);
                unsigned p = (unsigned)(i * 4 + c);
                if (pos < CAP) cand[pos] = ((unsigned long long)key << 32) | (unsigned)(~p);
            }
        }
    }
    __syncthreads();
    unsigned cc = scal[1]; if (cc > CAP) cc = CAP;
    for (unsigned i = tid; i < CAP; i += 256) if (i >= cc) cand[i] = 0ull;
    __syncthreads();
    // phase 4: bitonic sort desc
    for (unsigned k = 2; k <= CAP; k <<= 1)
        for (unsigned j = k >> 1; j; j >>= 1) {
            for (unsigned i = tid; i < CAP; i += 256) {
                unsigned l = i ^ j;
                if (l > i) {
                    unsigned long long a = cand[i], bq = cand[l];
                    bool sw = ((i & k) == 0) ? (a < bq) : (a > bq);
                    if (sw) { cand[i] = bq; cand[l] = a; }
                }
            }
            __syncthreads();
        }
}

// -------- Kernel kSel: per (b,c) top-400, IoU bitmask, greedy NMS ----------
struct HistU { unsigned hist[1024]; unsigned aux[256]; };
union SelU { HistU s; unsigned iouRow[TOPK][13]; };

__global__ __launch_bounds__(256) void kSel(const float* __restrict__ scoresT,
                                            const float4* __restrict__ boxes,
                                            float* __restrict__ detS,
                                            float4* __restrict__ detB) {
    __shared__ unsigned long long cand[CAP];
    __shared__ float4 selBox[TOPK];
    __shared__ float selArea[TOPK];
    __shared__ unsigned scal[4];
    __shared__ SelU U;
    __shared__ unsigned keptWords[13];

    int b = blockIdx.x / NCLS, c = blockIdx.x % NCLS;
    int tid = threadIdx.x;
    const float* src = scoresT + (size_t)(b * NCLS + c) * NP;

    select_desc(src, NP, TOPK, cand, U.s.hist, U.s.aux, scal, tid);

    for (int k = tid; k < TOPK; k += 256) {
        unsigned idx = ~(unsigned)cand[k];
        if (idx >= NP) idx = 0;
        float4 bx = boxes[(size_t)b * NP + idx];
        selBox[k] = bx;
        selArea[k] = (bx.z - bx.x) * (bx.w - bx.y);
    }
    __syncthreads();

    for (int r = tid; r < TOPK; r += 256) {
        float4 br = selBox[r];
        float ar = selArea[r];
        unsigned word = 0;
        for (int j = 0; j < TOPK; ++j) {
            float4 bj = selBox[j];
            float ix = fminf(br.z, bj.z) - fmaxf(br.x, bj.x);
            float iy = fminf(br.w, bj.w) - fmaxf(br.y, bj.y);
            float inter = fmaxf(ix, 0.f) * fmaxf(iy, 0.f);
            float uni = ar + selArea[j] - inter;
            bool sup = inter > 0.45f * uni;
            word |= (unsigned)sup << (j & 31);
            if ((j & 31) == 31) { U.iouRow[r][j >> 5] = word; word = 0; }
        }
        U.iouRow[r][12] = word;
    }
    __syncthreads();

    if (tid < 64) {
        unsigned lane = tid;
        unsigned myKept = 0;
        const unsigned VALID_KEY = f2ord(0.01f);
        for (int i = 0; i < TOPK; ++i) {
            unsigned w = (lane < 13) ? U.iouRow[i][lane] : 0u;
            bool hit = (w & myKept) != 0u;
            unsigned long long bal = __ballot(hit);
            unsigned keyi = (unsigned)(cand[i] >> 32);
            bool kept = (keyi > VALID_KEY) && (bal == 0ull);
            if (kept && lane == (unsigned)(i >> 5)) myKept |= 1u << (i & 31);
        }
        if (lane < 13) keptWords[lane] = myKept;
    }
    __syncthreads();

    size_t obase = (size_t)b * DETN + (size_t)c * TOPK;
    for (int k = tid; k < TOPK; k += 256) {
        bool kept = (keptWords[k >> 5] >> (k & 31)) & 1u;
        float s = ord2f((unsigned)(cand[k] >> 32));
        detS[obase + k] = kept ? s : -1.0f;
        detB[obase + k] = selBox[k];
    }
}

// -------- Kernel C: per-batch stable top-200 + rasterize -------------------
__global__ __launch_bounds__(256) void kC(const float* __restrict__ detS,
                                          const float4* __restrict__ detB,
                                          float* __restrict__ out) {
    __shared__ unsigned long long cand[CAP];
    __shared__ HistU S;
    __shared__ unsigned scal[4];
    __shared__ float eS[KEEPK];
    __shared__ int eC0[KEEPK], eC1[KEEPK], eC2[KEEPK], eC3[KEEPK];
    __shared__ int eCh[KEEPK];

    int b = blockIdx.x;
    int tid = threadIdx.x;

    select_desc(detS + (size_t)b * DETN, DETN, KEEPK, cand, S.hist, S.aux, scal, tid);

    for (int k = tid; k < KEEPK; k += 256) {
        unsigned long long K = cand[k];
        unsigned key = (unsigned)(K >> 32);
        unsigned idx = ~(unsigned)K;
        if (idx >= DETN) idx = 0;
        float s = ord2f(key);
        float4 bx = detB[(size_t)b * DETN + idx];
        eS[k] = (key == 0u) ? -1.0f : s;
        eC0[k] = (int)rintf(bx.x * (float)OUTS);
        eC1[k] = (int)rintf(bx.y * (float)OUTS);
        eC2[k] = (int)rintf(bx.z * (float)OUTS);
        eC3[k] = (int)rintf(bx.w * (float)OUTS);
        eCh[k] = (int)(idx / TOPK);
    }
    __syncthreads();

    for (int cell = tid; cell < NCELL; cell += 256) {
        int y = cell / OUTS, x = cell % OUTS;
        float* o = out + ((size_t)b * NCELL + cell) * 81;
        for (int ch = 0; ch < 81; ++ch) o[ch] = 0.f;
        for (int k = 0; k < KEEPK; ++k) {
            float s = eS[k];
            if (s < 0.6f) continue;
            if (y >= eC1[k] && y < eC3[k] && x >= eC0[k] && x < eC2[k])
                o[eCh[k]] = s;
        }
    }
}

extern "C" void kernel_launch(void* const* d_in, const int* in_sizes, int n_in,
                              void* d_out, int out_size, void* d_ws, size_t ws_size,
                              hipStream_t stream) {
    const float* x = (const float*)d_in[0];
    float* out = (float*)d_out;

    float4* boxes   = (float4*)d_ws;                         // NB*NP float4
    float4* detB    = boxes + (size_t)NB * NP;               // NB*DETN float4
    float*  scoresT = (float*)(detB + (size_t)NB * DETN);    // NB*NCLS*NP floats
    float*  detS    = scoresT + (size_t)NB * NCLS * NP;      // NB*DETN floats

    kA<<<NB * CHUNKS, 256, 0, stream>>>(x, scoresT, boxes);
    kSel<<<NB * NCLS, 256, 0, stream>>>(scoresT, boxes, detS, detB);
    kC<<<NB, 256, 0, stream>>>(detS, detB, out);
}

// Round 4
// 344.771 us; speedup vs baseline: 1.7095x; 1.1899x over previous
//
#include <hip/hip_runtime.h>

#define NB 8
#define NP 24564
#define NCLS 80          // foreground classes
#define TOPK 400
#define KEEPK 200
#define OUTS 19
#define NCELL (OUTS * OUTS)   // 361
#define DETN (NCLS * TOPK)    // 32000 per batch
#define CKS 32008             // compact-key stride per batch (16B-aligned)
#define ROWS 64
#define CHUNKS ((NP + ROWS - 1) / ROWS)   // 384
#define CAP 1024

__device__ __forceinline__ unsigned f2ord(float f) {
    unsigned u = __float_as_uint(f);
    return (u & 0x80000000u) ? ~u : (u | 0x80000000u);
}
__device__ __forceinline__ float ord2f(unsigned k) {
    unsigned u = (k & 0x80000000u) ? (k & 0x7fffffffu) : ~k;
    return __uint_as_float(u);
}
// 1024 bins over key top-16-bits; valid scores (0.01,1] map to [0x23,0x380].
__device__ __forceinline__ unsigned bin16(unsigned key) {
    int b = (int)(key >> 16) - 0xBC00;
    b = b < 0 ? 0 : (b > 1023 ? 1023 : b);
    return (unsigned)b;
}

// ---------------- Kernel A: transpose scores + decode boxes ----------------
__global__ __launch_bounds__(256) void kA(const float* __restrict__ x,
                                          float* __restrict__ scoresT,
                                          float4* __restrict__ boxes,
                                          unsigned long long* __restrict__ ckeys,
                                          unsigned* __restrict__ cnt) {
    // zero compact-key buffer + counters (workspace is poisoned each launch)
    for (int i = blockIdx.x * 256 + threadIdx.x; i < NB * CKS; i += gridDim.x * 256)
        ckeys[i] = 0ull;
    if (blockIdx.x == 0 && threadIdx.x < NB) cnt[threadIdx.x] = 0u;

    int blk = blockIdx.x;
    int b = blk / CHUNKS, chunk = blk % CHUNKS;
    int p0 = chunk * ROWS;
    int nrows = NP - p0; if (nrows > ROWS) nrows = ROWS;
    __shared__ float tile[ROWS * 93];
    const float* src = x + (size_t)(b * NP + p0) * 93;
    int total4 = (nrows * 93) >> 2;          // 64*93 and 52*93 both %4==0
    const float4* s4 = (const float4*)src;
    float4* t4 = (float4*)tile;
    for (int e = threadIdx.x; e < total4; e += 256) t4[e] = s4[e];
    __syncthreads();
    int row = threadIdx.x & 63;
    int cg = threadIdx.x >> 6;
    if (row < nrows) {
        for (int c = cg; c < NCLS; c += 4) {
            float v = tile[row * 93 + 5 + c];
            float m = (v > 0.01f) ? v : -1.0f;
            scoresT[(size_t)(b * NCLS + c) * NP + p0 + row] = m;
        }
    }
    if (threadIdx.x < nrows) {
        const float* r = tile + threadIdx.x * 93;
        float l0 = r[0], l1 = r[1], l2 = r[2], l3 = r[3];
        float px1 = r[85], py1 = r[86], px2 = r[87], py2 = r[88];
        float v0 = r[89], v1 = r[90], v2 = r[91], v3 = r[92];
        float pw = px2 - px1, ph = py2 - py1;
        float pcx = 0.5f * (px2 + px1), pcy = 0.5f * (py2 + py1);
        float cx = l0 * pw * v0 + pcx;
        float cy = l1 * pw * v1 + pcy;      // reference uses pw here too
        float w = expf(l2 * v2) * pw;
        float h = expf(l3 * v3) * ph;
        float x1 = fminf(fmaxf(cx - 0.5f * w, 0.f), 1.f);
        float y1 = fminf(fmaxf(cy - 0.5f * h, 0.f), 1.f);
        float x2 = fminf(fmaxf(cx + 0.5f * w, 0.f), 1.f);
        float y2 = fminf(fmaxf(cy + 0.5f * h, 0.f), 1.f);
        boxes[(size_t)b * NP + p0 + threadIdx.x] = make_float4(x1, y1, x2, y2);
    }
}

// --- exact top-k select (float src): hist1024 + optional byte refine -------
__device__ void select_desc(const float* __restrict__ src, int n, unsigned needed,
                            unsigned long long* cand,
                            unsigned* hist, unsigned* aux, unsigned* scal,
                            int tid) {
    for (int i = tid; i < 1024; i += 256) hist[i] = 0u;
    if (tid == 0) { scal[0] = 0u; scal[1] = 0u; scal[2] = 0u; scal[3] = 0u; }
    __syncthreads();
    const float4* src4 = (const float4*)src;
    int n4 = n >> 2;
    for (int i = tid; i < n4; i += 256) {
        float4 v = src4[i];
        atomicAdd(&hist[bin16(f2ord(v.x))], 1u);
        atomicAdd(&hist[bin16(f2ord(v.y))], 1u);
        atomicAdd(&hist[bin16(f2ord(v.z))], 1u);
        atomicAdd(&hist[bin16(f2ord(v.w))], 1u);
    }
    __syncthreads();
    unsigned h0 = hist[4 * tid], h1 = hist[4 * tid + 1];
    unsigned h2 = hist[4 * tid + 2], h3 = hist[4 * tid + 3];
    aux[tid] = h0 + h1 + h2 + h3;
    __syncthreads();
    for (int d = 1; d < 256; d <<= 1) {
        unsigned v = (tid + d < 256) ? aux[tid + d] : 0u;
        __syncthreads();
        aux[tid] += v;
        __syncthreads();
    }
    unsigned above = (tid < 255) ? aux[tid + 1] : 0u;
    unsigned s3 = above + h3, s2 = s3 + h2, s1 = s2 + h1, s0 = s1 + h0;
    if (s0 >= needed && s1 < needed) { scal[0] = 4 * tid;     scal[1] = s1;    scal[2] = s0; }
    if (s1 >= needed && s2 < needed) { scal[0] = 4 * tid + 1; scal[1] = s2;    scal[2] = s1; }
    if (s2 >= needed && s3 < needed) { scal[0] = 4 * tid + 2; scal[1] = s3;    scal[2] = s2; }
    if (s3 >= needed && above < needed) { scal[0] = 4 * tid + 3; scal[1] = above; scal[2] = s3; }
    __syncthreads();
    unsigned cb = scal[0], countHigh = scal[1], countAt = scal[2];
    unsigned cut8 = 0;
    if (countAt > CAP) {   // uniform branch: refine cut bin by key[15:8]
        aux[tid] = 0u;
        __syncthreads();
        for (int i = tid; i < n4; i += 256) {
            float4 v = src4[i];
            unsigned k0 = f2ord(v.x), k1 = f2ord(v.y), k2 = f2ord(v.z), k3 = f2ord(v.w);
            if (bin16(k0) == cb) atomicAdd(&aux[(k0 >> 8) & 255u], 1u);
            if (bin16(k1) == cb) atomicAdd(&aux[(k1 >> 8) & 255u], 1u);
            if (bin16(k2) == cb) atomicAdd(&aux[(k2 >> 8) & 255u], 1u);
            if (bin16(k3) == cb) atomicAdd(&aux[(k3 >> 8) & 255u], 1u);
        }
        __syncthreads();
        for (int d = 1; d < 256; d <<= 1) {
            unsigned v = (tid + d < 256) ? aux[tid + d] : 0u;
            __syncthreads();
            aux[tid] += v;
            __syncthreads();
        }
        unsigned suf8 = aux[tid];
        unsigned sufN = (tid < 255) ? aux[tid + 1] : 0u;
        unsigned need2 = needed - countHigh;
        if (suf8 >= need2 && sufN < need2) scal[3] = (unsigned)tid;
        __syncthreads();
        cut8 = scal[3];
    }
    __syncthreads();
    if (tid == 0) scal[1] = 0u;
    __syncthreads();
    for (int i = tid; i < n4; i += 256) {
        float4 v = src4[i];
        unsigned kk[4] = { f2ord(v.x), f2ord(v.y), f2ord(v.z), f2ord(v.w) };
#pragma unroll
        for (int c = 0; c < 4; ++c) {
            unsigned key = kk[c];
            unsigned b16 = bin16(key);
            bool take = (b16 > cb) || (b16 == cb && ((key >> 8) & 255u) >= cut8);
            if (take) {
                unsigned pos = atomicAdd(&scal[1], 1u);
                unsigned p = (unsigned)(i * 4 + c);
                if (pos < CAP) cand[pos] = ((unsigned long long)key << 32) | (unsigned)(~p);
            }
        }
    }
    __syncthreads();
    unsigned cc = scal[1]; if (cc > CAP) cc = CAP;
    for (unsigned i = tid; i < CAP; i += 256) if (i >= cc) cand[i] = 0ull;
    __syncthreads();
    unsigned S = (cc <= 512u) ? 512u : (unsigned)CAP;
    for (unsigned k = 2; k <= S; k <<= 1)
        for (unsigned j = k >> 1; j; j >>= 1) {
            for (unsigned i = tid; i < S; i += 256) {
                unsigned l = i ^ j;
                if (l > i) {
                    unsigned long long a = cand[i], bq = cand[l];
                    bool sw = ((i & k) == 0) ? (a < bq) : (a > bq);
                    if (sw) { cand[i] = bq; cand[l] = a; }
                }
            }
            __syncthreads();
        }
}

// -------- Kernel kSel: per (b,c) top-400, triangular IoU, NMS, compact -----
struct HistU { unsigned hist[1024]; unsigned aux[256]; };
union SelU { HistU s; unsigned iouRow[TOPK][13]; };

__global__ __launch_bounds__(256) void kSel(const float* __restrict__ scoresT,
                                            const float4* __restrict__ boxes,
                                            unsigned long long* __restrict__ ckeys,
                                            float4* __restrict__ cboxes,
                                            unsigned* __restrict__ cnt) {
    __shared__ unsigned long long cand[CAP];
    __shared__ float4 selBox[TOPK];
    __shared__ float selArea[TOPK];
    __shared__ unsigned scal[4];
    __shared__ SelU U;
    __shared__ unsigned keptWords[13];

    int b = blockIdx.x / NCLS, c = blockIdx.x % NCLS;
    int tid = threadIdx.x;
    const float* src = scoresT + (size_t)(b * NCLS + c) * NP;

    select_desc(src, NP, TOPK, cand, U.s.hist, U.s.aux, scal, tid);

    for (int k = tid; k < TOPK; k += 256) {
        unsigned idx = ~(unsigned)cand[k];
        if (idx >= NP) idx = 0;
        float4 bx = boxes[(size_t)b * NP + idx];
        selBox[k] = bx;
        selArea[k] = (bx.z - bx.x) * (bx.w - bx.y);
    }
    __syncthreads();

    // triangular IoU: row r only needs words 0..(r>>5); rows paired (t,399-t).
    // Bits j>i in word i>>5 and garbage words beyond are ANDed against zero
    // kept-mask bits in the NMS scan -> safe.
#pragma unroll 1
    for (int pass = 0; pass < 2; ++pass) {
        int r = (pass == 0) ? tid : 399 - tid;
        if (pass == 1 && tid >= 144) break;
        float4 br = selBox[r];
        float ar = selArea[r];
        int nw = (r >> 5) + 1;
        for (int w = 0; w < nw; ++w) {
            unsigned word = 0;
#pragma unroll 8
            for (int jj = 0; jj < 32; ++jj) {
                int j = w * 32 + jj;
                float4 bj = selBox[j];
                float ix = fminf(br.z, bj.z) - fmaxf(br.x, bj.x);
                float iy = fminf(br.w, bj.w) - fmaxf(br.y, bj.y);
                float inter = fmaxf(ix, 0.f) * fmaxf(iy, 0.f);
                float uni = ar + selArea[j] - inter;
                word |= (unsigned)(inter > 0.45f * uni) << jj;
            }
            U.iouRow[r][w] = word;
        }
    }
    __syncthreads();

    if (tid < 64) {
        unsigned lane = tid;
        unsigned myKept = 0;
        const unsigned VALID_KEY = f2ord(0.01f);
        for (int i = 0; i < TOPK; ++i) {
            unsigned w = (lane < 13) ? U.iouRow[i][lane] : 0u;
            bool hit = (w & myKept) != 0u;
            unsigned long long bal = __ballot(hit);
            unsigned keyi = (unsigned)(cand[i] >> 32);
            bool kept = (keyi > VALID_KEY) && (bal == 0ull);
            if (kept && lane == (unsigned)(i >> 5)) myKept |= 1u << (i & 31);
        }
        if (lane < 13) keptWords[lane] = myKept;
    }
    __syncthreads();

    // compact epilogue: kept entries -> per-batch list; boxes scattered by flat
    size_t kb = (size_t)b * CKS;
    size_t bb = (size_t)b * DETN;
    for (int k = tid; k < TOPK; k += 256) {
        unsigned flat = (unsigned)(c * TOPK + k);
        cboxes[bb + flat] = selBox[k];
        bool kept = (keptWords[k >> 5] >> (k & 31)) & 1u;
        if (kept) {
            unsigned key = (unsigned)(cand[k] >> 32);
            unsigned pos = atomicAdd(&cnt[b], 1u);
            ckeys[kb + pos] = ((unsigned long long)key << 32) | (unsigned)(~flat);
        }
    }
}

// -------- Kernel C: per-batch top-200 of compacted keys + rasterize --------
// NOTE: compacted scores concentrate in (~0.984, 1] (already per-class
// top-400) -> only ~6 bin16 bins populated; the byte refine is MANDATORY.
__global__ __launch_bounds__(256) void kC(const unsigned long long* __restrict__ ckeys,
                                          const float4* __restrict__ cboxes,
                                          const unsigned* __restrict__ cnt,
                                          float* __restrict__ out) {
    __shared__ unsigned long long cand[CAP];
    __shared__ HistU S;
    __shared__ unsigned scal[4];
    __shared__ float eS[KEEPK];
    __shared__ int eC0[KEEPK], eC1[KEEPK], eC2[KEEPK], eC3[KEEPK];
    __shared__ int eCh[KEEPK];

    int b = blockIdx.x;
    int tid = threadIdx.x;
    const ulonglong2* k2 = (const ulonglong2*)(ckeys + (size_t)b * CKS);
    int n = (int)cnt[b]; if (n > DETN) n = DETN;
    int n2 = (n + 1) >> 1;           // buffer pre-zeroed by kA -> safe pair reads
    const unsigned needed = KEEPK;

    for (int i = tid; i < 1024; i += 256) S.hist[i] = 0u;
    if (tid == 0) { scal[0] = 0u; scal[1] = 0u; scal[2] = 0u; scal[3] = 0u; }
    __syncthreads();
    for (int i = tid; i < n2; i += 256) {
        ulonglong2 v = k2[i];
        atomicAdd(&S.hist[bin16((unsigned)(v.x >> 32))], 1u);
        atomicAdd(&S.hist[bin16((unsigned)(v.y >> 32))], 1u);
    }
    __syncthreads();
    unsigned h0 = S.hist[4 * tid], h1 = S.hist[4 * tid + 1];
    unsigned h2 = S.hist[4 * tid + 2], h3 = S.hist[4 * tid + 3];
    S.aux[tid] = h0 + h1 + h2 + h3;
    __syncthreads();
    for (int d = 1; d < 256; d <<= 1) {
        unsigned v = (tid + d < 256) ? S.aux[tid + d] : 0u;
        __syncthreads();
        S.aux[tid] += v;
        __syncthreads();
    }
    unsigned above = (tid < 255) ? S.aux[tid + 1] : 0u;
    unsigned s3 = above + h3, s2 = s3 + h2, s1 = s2 + h1, s0 = s1 + h0;
    if (s0 >= needed && s1 < needed) { scal[0] = 4 * tid;     scal[1] = s1;    scal[2] = s0; }
    if (s1 >= needed && s2 < needed) { scal[0] = 4 * tid + 1; scal[1] = s2;    scal[2] = s1; }
    if (s2 >= needed && s3 < needed) { scal[0] = 4 * tid + 2; scal[1] = s3;    scal[2] = s2; }
    if (s3 >= needed && above < needed) { scal[0] = 4 * tid + 3; scal[1] = above; scal[2] = s3; }
    __syncthreads();
    unsigned cb = scal[0], countHigh = scal[1], countAt = scal[2];
    unsigned cut8 = 0;
    if (countAt > CAP) {   // byte refine on key[15:8] within cut bin
        S.aux[tid] = 0u;
        __syncthreads();
        for (int i = tid; i < n2; i += 256) {
            ulonglong2 v = k2[i];
            unsigned kx = (unsigned)(v.x >> 32), ky = (unsigned)(v.y >> 32);
            if (bin16(kx) == cb) atomicAdd(&S.aux[(kx >> 8) & 255u], 1u);
            if (bin16(ky) == cb) atomicAdd(&S.aux[(ky >> 8) & 255u], 1u);
        }
        __syncthreads();
        for (int d = 1; d < 256; d <<= 1) {
            unsigned v = (tid + d < 256) ? S.aux[tid + d] : 0u;
            __syncthreads();
            S.aux[tid] += v;
            __syncthreads();
        }
        unsigned suf8 = S.aux[tid];
        unsigned sufN = (tid < 255) ? S.aux[tid + 1] : 0u;
        unsigned need2 = needed - countHigh;
        if (suf8 >= need2 && sufN < need2) scal[3] = (unsigned)tid;
        __syncthreads();
        cut8 = scal[3];
    }
    __syncthreads();
    if (tid == 0) scal[1] = 0u;
    __syncthreads();
    for (int i = tid; i < n2; i += 256) {
        ulonglong2 v = k2[i];
#pragma unroll
        for (int c = 0; c < 2; ++c) {
            unsigned long long key = c ? v.y : v.x;
            unsigned kh = (unsigned)(key >> 32);
            unsigned b16 = bin16(kh);
            bool take = (b16 > cb) || (b16 == cb && ((kh >> 8) & 255u) >= cut8);
            if (take) {
                unsigned pos = atomicAdd(&scal[1], 1u);
                if (pos < CAP) cand[pos] = key;
            }
        }
    }
    __syncthreads();
    unsigned cc = scal[1]; if (cc > CAP) cc = CAP;
    for (unsigned i = tid; i < CAP; i += 256) if (i >= cc) cand[i] = 0ull;
    __syncthreads();
    unsigned Sn = (cc <= 512u) ? 512u : (unsigned)CAP;
    for (unsigned k = 2; k <= Sn; k <<= 1)
        for (unsigned j = k >> 1; j; j >>= 1) {
            for (unsigned i = tid; i < Sn; i += 256) {
                unsigned l = i ^ j;
                if (l > i) {
                    unsigned long long a = cand[i], bq = cand[l];
                    bool sw = ((i & k) == 0) ? (a < bq) : (a > bq);
                    if (sw) { cand[i] = bq; cand[l] = a; }
                }
            }
            __syncthreads();
        }

    for (int k = tid; k < KEEPK; k += 256) {
        unsigned long long K = cand[k];
        unsigned key = (unsigned)(K >> 32);
        unsigned flat = ~(unsigned)K;
        if (flat >= DETN) flat = 0;
        float4 bx = cboxes[(size_t)b * DETN + flat];
        eS[k] = (key == 0u) ? -1.0f : ord2f(key);
        eC0[k] = (int)rintf(bx.x * (float)OUTS);
        eC1[k] = (int)rintf(bx.y * (float)OUTS);
        eC2[k] = (int)rintf(bx.z * (float)OUTS);
        eC3[k] = (int)rintf(bx.w * (float)OUTS);
        eCh[k] = (int)(flat / TOPK);
    }
    __syncthreads();

    for (int cell = tid; cell < NCELL; cell += 256) {
        int y = cell / OUTS, x = cell % OUTS;
        float* o = out + ((size_t)b * NCELL + cell) * 81;
        for (int ch = 0; ch < 81; ++ch) o[ch] = 0.f;
        for (int k = 0; k < KEEPK; ++k) {
            float s = eS[k];
            if (s < 0.6f) continue;
            if (y >= eC1[k] && y < eC3[k] && x >= eC0[k] && x < eC2[k])
                o[eCh[k]] = s;
        }
    }
}

extern "C" void kernel_launch(void* const* d_in, const int* in_sizes, int n_in,
                              void* d_out, int out_size, void* d_ws, size_t ws_size,
                              hipStream_t stream) {
    const float* x = (const float*)d_in[0];
    float* out = (float*)d_out;

    float4* boxes   = (float4*)d_ws;                          // NB*NP
    float4* cboxes  = boxes + (size_t)NB * NP;                // NB*DETN
    unsigned long long* ckeys = (unsigned long long*)(cboxes + (size_t)NB * DETN); // NB*CKS
    float*  scoresT = (float*)(ckeys + (size_t)NB * CKS);     // NB*NCLS*NP
    unsigned* cnt   = (unsigned*)(scoresT + (size_t)NB * NCLS * NP);  // NB

    kA<<<NB * CHUNKS, 256, 0, stream>>>(x, scoresT, boxes, ckeys, cnt);
    kSel<<<NB * NCLS, 256, 0, stream>>>(scoresT, boxes, ckeys, cboxes, cnt);
    kC<<<NB, 256, 0, stream>>>(ckeys, cboxes, cnt, out);
}